// Round 12
// baseline (144.487 us; speedup 1.0000x reference)
//
#include <hip/hip_runtime.h>

// CRITICAL: hipcc defaults to -ffp-contract=fast-honor-pragmas; plain ops
// with this pragma are guaranteed un-fused rn mul/add — rounding matches
// numpy exactly (proven absmax == 0.0 since R4).
#pragma clang fp contract(off)

// HISTORY: R9-R19 exhausted every micro-lever inside the "LDS key table +
// per-lane ds_read" structure: remat (R12), occupancy (R13), pk-rate
// (R14/R16), prefetch (R15), read dedup (R17), reads/eval (R18/R19 — void,
// allocator pins 64 VGPRs regardless of launch_bounds/waves_per_eu knobs).
// Robust facts: wall ≈ 2x VALU demand (~50% busy corrected), invariant to
// everything tried; bank conflicts ≈ 2% of wall; VALUBusy counter is
// instrs*4cyc/elapsed (R16 >100%). R20 pivots the STRUCTURE: lanes<->points,
// waves<->key-chunks => keys are wave-uniform => s_load through the scalar
// cache; ZERO LDS / vector-mem / lgkmcnt in the inner loop. LDS (32 KB)
// only for the final 16-way merge.
static __device__ __forceinline__ float min3f(float a, float b, float c) {
    float d;
    asm("v_min3_f32 %0, %1, %2, %3" : "=v"(d) : "v"(a), "v"(b), "v"(c));
    return d;
}

// Problem constants (from reference): B=4, N=16384, M=4096, D=64
#define MM 4096
#define DD 64
#define BN 65536                  // B*N points
#define FEATS_OFF 0               // feats: BN*DD floats
#define IDS_OFF (BN * DD)         // ids:   BN floats (ints stored as float)
#define PC_OFF (IDS_OFF + BN)     // pc:    BN*3 floats passthrough

#define BLK 1024                  // threads per block (16 waves)
#define WV 16                     // waves per block (= key chunks)
#define PP 4                      // points per lane
#define PTB (64 * PP)             // 256 points per block
#define NBLK (BN / PTB)           // 256 blocks (1 per CU)
#define KCH (MM / WV)             // 256 keys per wave chunk
#define NG (KCH / 4)              // 64 groups of 4 keys per chunk

// NUMERICS (bit-exact vs numpy fp32 replay — orders verified R4-R19):
//  - transform: kx' = -2.0f*kx (exact: sign+exponent), ksq = ((kx*kx +
//    ky*ky) + kz*kz) — same order as reference k_sq and all prior rounds.
//  - eval: cr = ((px*kx' + py*ky') + pz*kz'); d = (psq + cr) + ksq — the
//    verified sequence (== (psq - 2*cross) + ksq bit-exact). PSQ order
//    ((x2+y2)+z2) matches reference. FMA / MFMA / reassociation FORBIDDEN.
//  - argmin: bd via 2x v_min3 per 4-key group (== sequential strict-'<'
//    min, no NaNs); bg = first group where bd strictly dropped (later
//    equal values don't overwrite => first-group kept); within-group
//    first index via chained-ternary on recovery (smallest q with
//    dq == bd); cross-wave merge is lexicographic (d, id) with ids
//    monotone in wave => global first-index argmin.
__global__ __launch_bounds__(BLK)
void quant_embed_kernel(const float* __restrict__ pc,
                        const float* __restrict__ keys,
                        const float* __restrict__ values,
                        float* __restrict__ out)
{
#pragma clang fp contract(off)
    __shared__ float md[WV * PTB];   // 16 KB: candidate d per wave per point
    __shared__ int   mi[WV * PTB];   // 16 KB: candidate id per wave per point

    const int tid = threadIdx.x;
    const int l = tid & 63;                                   // lane
    const int w = __builtin_amdgcn_readfirstlane(tid >> 6);   // wave 0..15
    const int pbase = blockIdx.x * PTB;                       // block's first point

    // pc passthrough: 256 points = 768 floats = 192 float4.
    {
        const int base = blockIdx.x * (PTB * 3 / 4);
        if (tid < PTB * 3 / 4) {
            ((float4*)(out + PC_OFF))[base + tid] =
                ((const float4*)pc)[base + tid];
        }
    }

    // Lane's points: p_i = pbase + i*64 + l (coalesced: lanes consecutive).
    float PX[PP], PY[PP], PZ[PP], PSQ[PP], bd[PP];
    int bg[PP];
    #pragma unroll
    for (int i = 0; i < PP; ++i) {
        const int p = pbase + i * 64 + l;
        const float px = pc[3 * p + 0];
        const float py = pc[3 * p + 1];
        const float pz = pc[3 * p + 2];
        PX[i] = px; PY[i] = py; PZ[i] = pz;
        PSQ[i] = ((px * px) + (py * py)) + (pz * pz);
        bd[i] = 3.402823466e38f;
        bg[i] = 0;
    }

    // Main loop: wave w scans keys [w*KCH, (w+1)*KCH) in 4-key groups.
    // Group t covers keys 4*(w*NG + t) + {0,1,2,3}. All key data is
    // wave-uniform => s_load_dwordx4 x3 via the scalar cache. No LDS.
    const float4* kv4 = (const float4*)keys;
    const int gbase = w * NG;
    #pragma unroll 2
    for (int t = 0; t < NG; ++t) {
        const int G = gbase + t;
        const float4 ka = kv4[3 * G + 0];  // x0 y0 z0 x1
        const float4 kb = kv4[3 * G + 1];  // y1 z1 x2 y2
        const float4 kc = kv4[3 * G + 2];  // z2 x3 y3 z3
        const float kx0 = ka.x, ky0 = ka.y, kz0 = ka.z;
        const float kx1 = ka.w, ky1 = kb.x, kz1 = kb.y;
        const float kx2 = kb.z, ky2 = kb.w, kz2 = kc.x;
        const float kx3 = kc.y, ky3 = kc.z, kz3 = kc.w;
        // Transform (wave-uniform values; amortized over 4*64*PP evals):
        const float tx0 = -2.0f * kx0, ty0 = -2.0f * ky0, tz0 = -2.0f * kz0;
        const float tx1 = -2.0f * kx1, ty1 = -2.0f * ky1, tz1 = -2.0f * kz1;
        const float tx2 = -2.0f * kx2, ty2 = -2.0f * ky2, tz2 = -2.0f * kz2;
        const float tx3 = -2.0f * kx3, ty3 = -2.0f * ky3, tz3 = -2.0f * kz3;
        const float ts0 = ((kx0 * kx0) + (ky0 * ky0)) + (kz0 * kz0);
        const float ts1 = ((kx1 * kx1) + (ky1 * ky1)) + (kz1 * kz1);
        const float ts2 = ((kx2 * kx2) + (ky2 * ky2)) + (kz2 * kz2);
        const float ts3 = ((kx3 * kx3) + (ky3 * ky3)) + (kz3 * kz3);
        #pragma unroll
        for (int i = 0; i < PP; ++i) {
            const float c0 = ((PX[i] * tx0) + (PY[i] * ty0)) + (PZ[i] * tz0);
            const float d0 = (PSQ[i] + c0) + ts0;
            const float c1 = ((PX[i] * tx1) + (PY[i] * ty1)) + (PZ[i] * tz1);
            const float d1 = (PSQ[i] + c1) + ts1;
            const float c2 = ((PX[i] * tx2) + (PY[i] * ty2)) + (PZ[i] * tz2);
            const float d2 = (PSQ[i] + c2) + ts2;
            const float c3 = ((PX[i] * tx3) + (PY[i] * ty3)) + (PZ[i] * tz3);
            const float d3 = (PSQ[i] + c3) + ts3;
            float nb = min3f(bd[i], d0, d1);
            nb = min3f(nb, d2, d3);
            const bool ch = nb < bd[i];   // strict drop => first group kept
            bd[i] = nb;
            bg[i] = ch ? t : bg[i];
        }
    }

    // Recovery: re-evaluate group bg[i] (per-lane divergent => vector loads,
    // keys are L2-hot). Bit-identical recomputation; smallest q on ties.
    int bm[PP];
    #pragma unroll
    for (int i = 0; i < PP; ++i) {
        const int G = gbase + bg[i];
        const float4 ka = kv4[3 * G + 0];
        const float4 kb = kv4[3 * G + 1];
        const float4 kc = kv4[3 * G + 2];
        const float kxq[4] = {ka.x, ka.w, kb.z, kc.y};
        const float kyq[4] = {ka.y, kb.x, kb.w, kc.z};
        const float kzq[4] = {ka.z, kb.y, kc.x, kc.w};
        int m = 4 * G + 3;   // fallback: q=3
        #pragma unroll
        for (int q = 3; q >= 0; --q) {  // descending => smallest matching q wins
            const float tx = -2.0f * kxq[q];
            const float ty = -2.0f * kyq[q];
            const float tz = -2.0f * kzq[q];
            const float ts = ((kxq[q] * kxq[q]) + (kyq[q] * kyq[q])) + (kzq[q] * kzq[q]);
            const float cr = ((PX[i] * tx) + (PY[i] * ty)) + (PZ[i] * tz);
            const float dq = (PSQ[i] + cr) + ts;
            if (dq == bd[i]) m = 4 * G + q;
        }
        bm[i] = m;
    }

    // Cross-wave merge: 16 candidates per point, lexicographic (d, id).
    #pragma unroll
    for (int i = 0; i < PP; ++i) {
        md[w * PTB + i * 64 + l] = bd[i];
        mi[w * PTB + i * 64 + l] = bm[i];
    }
    __syncthreads();
    if (tid < PTB) {
        float d = md[tid];
        int   m = mi[tid];
        #pragma unroll
        for (int ww = 1; ww < WV; ++ww) {
            const float od = md[ww * PTB + tid];
            const int   om = mi[ww * PTB + tid];
            if (od < d || (od == d && om < m)) { d = od; m = om; }
        }
        mi[tid] = m;  // final id for point tid (wave-0 slots already consumed)
        out[IDS_OFF + pbase + tid] = (float)m;
    }
    __syncthreads();

    // Feats gather: wave w copies rows for points [w*16, w*16+16).
    #pragma unroll
    for (int r = 0; r < PTB / WV; ++r) {
        const int p = w * (PTB / WV) + r;
        const int mm = mi[p];   // uniform within wave
        out[FEATS_OFF + (size_t)(pbase + p) * DD + l] =
            values[(size_t)mm * DD + l];
    }
}

extern "C" void kernel_launch(void* const* d_in, const int* in_sizes, int n_in,
                              void* d_out, int out_size, void* d_ws, size_t ws_size,
                              hipStream_t stream) {
    const float* pc     = (const float*)d_in[0];
    const float* keys   = (const float*)d_in[1];
    const float* values = (const float*)d_in[2];
    float* out = (float*)d_out;

    dim3 grid(NBLK);   // 256 blocks of 1024 threads = 1 block/CU, no tail
    dim3 block(BLK);
    quant_embed_kernel<<<grid, block, 0, stream>>>(pc, keys, values, out);
}